// Round 7
// baseline (2136.420 us; speedup 1.0000x reference)
//
#include <hip/hip_runtime.h>
#include <stdint.h>

#define N_USERS 100000
#define N_NODES 150000
#define D0      128
#define H1      256
#define H2      128
#define NEDGE   4800000
#define BATCH   16384
#define EPSV    1e-5f
#define BSHIFT  9            // 512-row buckets
#define BROWS   512
#define NBUCK   293          // ceil(150000/512)
#define BCHUNK  4096         // edges per k_bucket block
#define CCHUNK  16384        // edges per k_bcount block

typedef short short8  __attribute__((ext_vector_type(8)));   // 8 bf16 MFMA frag
typedef float floatx4 __attribute__((ext_vector_type(4)));
typedef unsigned short u16;

__device__ inline float bf2f(u16 u) {
    union { float f; uint32_t i; } x; x.i = ((uint32_t)u) << 16; return x.f;
}
__device__ inline u16 f2bf(float f) {
    union { float f; uint32_t i; } x; x.f = f;
    return (u16)((x.i + 0x7FFFu + ((x.i >> 16) & 1u)) >> 16);  // RNE
}
__device__ inline float itof(uint32_t u) {
    union { float f; uint32_t i; } x; x.i = u; return x.f;
}
__device__ inline uint32_t ftoi(float f) {
    union { float f; uint32_t i; } x; x.f = f; return x.i;
}
__device__ inline uint32_t pack2(float a, float b) {
    return (uint32_t)f2bf(a) | ((uint32_t)f2bf(b) << 16);
}

// ---------------- fused init: canary + zeros ----------------
__global__ __launch_bounds__(256) void k_init(float* __restrict__ out, int out_n,
                                              int* __restrict__ bcount,
                                              double* __restrict__ stats1,
                                              double* __restrict__ stats2) {
    int i = blockIdx.x * 256 + threadIdx.x;
    if (i < out_n) out[i] = 2.0f;               // canary
    if (i < NBUCK + 1) bcount[i] = 0;
    if (i < 2 * H1) stats1[i] = 0.0;
    if (i < 2 * H2) stats2[i] = 0.0;
}

// ---------------- x (fp32 user||item) -> bf16 xb ----------------
__global__ __launch_bounds__(256) void k_cvt(const float* __restrict__ ue,
                                             const float* __restrict__ ie,
                                             u16* __restrict__ xb) {
    int i = (blockIdx.x * 256 + threadIdx.x) * 4;
    const int NU = N_USERS * D0;
    const int NT = N_NODES * D0;
    if (i >= NT) return;
    const float* src = (i < NU) ? (ue + i) : (ie + (i - NU));
    float4 f = *(const float4*)(const void*)src;
    uint2 w;
    w.x = pack2(f.x, f.y);
    w.y = pack2(f.z, f.w);
    *(uint2*)(void*)(xb + i) = w;
}

// ---------------- bucket counting: LDS histogram of 293 buckets ----------------
__global__ __launch_bounds__(256) void k_bcount(const int* __restrict__ rows,
                                                int* __restrict__ bcount) {
    __shared__ int h[NBUCK];
    int tid = threadIdx.x;
    for (int i = tid; i < NBUCK; i += 256) h[i] = 0;
    __syncthreads();
    int e0 = blockIdx.x * CCHUNK;
    int nE = NEDGE - e0; if (nE > CCHUNK) nE = CCHUNK;
    for (int i = tid; i < nE; i += 256) atomicAdd(&h[rows[e0 + i] >> BSHIFT], 1);
    __syncthreads();
    for (int i = tid; i < NBUCK; i += 256)
        if (h[i] > 0) atomicAdd(&bcount[i], h[i]);
}

// single-block (512t) scan of bucket counts -> bucket_base / bucket_cursor; row_ptr[N]=NEDGE
__global__ __launch_bounds__(512) void k_bscan(const int* __restrict__ bcount,
                                               int* __restrict__ bucket_base,
                                               int* __restrict__ bucket_cursor,
                                               int* __restrict__ row_ptr) {
    int tid = threadIdx.x;
    int c = (tid < NBUCK) ? bcount[tid] : 0;
    int lane = tid & 63, wid = tid >> 6;
    int v = c;
    for (int off = 1; off < 64; off <<= 1) {
        int u = __shfl_up(v, off, 64);
        if (lane >= off) v += u;
    }
    __shared__ int wsum[8];
    if (lane == 63) wsum[wid] = v;
    __syncthreads();
    if (tid == 0) {
        int acc = 0;
        for (int w = 0; w < 8; ++w) { int t = wsum[w]; wsum[w] = acc; acc += t; }
    }
    __syncthreads();
    int ex = wsum[wid] + (v - c);
    if (tid < NBUCK) { bucket_base[tid] = ex; bucket_cursor[tid] = ex; }
    if (tid == 0) { bucket_base[NBUCK] = NEDGE; row_ptr[N_NODES] = NEDGE; }
}

// ---------------- pass 1: LDS-staged bucket append (coalesced spans) ----------------
// payload packed: x = (rowlocal<<18) | col  (9b rowlocal + 18b col), y = val bits
__global__ __launch_bounds__(256) void k_bucket(const int* __restrict__ rows,
                                                const int* __restrict__ cols,
                                                const float* __restrict__ vals,
                                                int* __restrict__ bucket_cursor,
                                                uint2* __restrict__ etmp) {
    __shared__ uint2 stage[BCHUNK];        // 32 KB
    __shared__ u16   slotb[BCHUNK];        // 8 KB
    __shared__ int   lcnt[NBUCK + 1];
    __shared__ int   lscan[NBUCK + 1];
    __shared__ int   gstart[NBUCK];
    __shared__ int   wsum[8];
    int tid = threadIdx.x;
    int e0 = blockIdx.x * BCHUNK;
    int nE = NEDGE - e0; if (nE > BCHUNK) nE = BCHUNK;

    for (int i = tid; i <= NBUCK; i += 256) lcnt[i] = 0;
    __syncthreads();
    for (int i = tid; i < nE; i += 256) atomicAdd(&lcnt[rows[e0 + i] >> BSHIFT], 1);
    __syncthreads();
    // two-round wave scan over 293 entries using 256 threads (handle idx and idx+256)
    {
        int lane = tid & 63, wid = tid >> 6;
        int c0 = lcnt[tid];
        int c1 = (tid + 256 <= NBUCK) ? lcnt[tid + 256] : 0;   // lcnt has NBUCK+1 slots
        if (tid < NBUCK) gstart[tid] = atomicAdd(&bucket_cursor[tid], c0);
        if (tid + 256 < NBUCK) gstart[tid + 256] = atomicAdd(&bucket_cursor[tid + 256], c1);
        int v = c0;
        for (int off = 1; off < 64; off <<= 1) {
            int u = __shfl_up(v, off, 64);
            if (lane >= off) v += u;
        }
        if (lane == 63) wsum[wid] = v;
        __syncthreads();
        int v1 = c1;
        for (int off = 1; off < 64; off <<= 1) {
            int u = __shfl_up(v1, off, 64);
            if (lane >= off) v1 += u;
        }
        if (lane == 63) wsum[4 + wid] = v1;
        __syncthreads();
        if (tid == 0) {
            int acc = 0;
            for (int w = 0; w < 8; ++w) { int t = wsum[w]; wsum[w] = acc; acc += t; }
        }
        __syncthreads();
        if (tid < NBUCK) lscan[tid] = wsum[wid] + (v - c0);
        if (tid + 256 < NBUCK) lscan[tid + 256] = wsum[4 + wid] + (v1 - c1);
        __syncthreads();
        for (int i = tid; i < NBUCK; i += 256) lcnt[i] = 0;
    }
    __syncthreads();
    for (int i = tid; i < nE; i += 256) {
        int r = rows[e0 + i];
        int b = r >> BSHIFT;
        int lidx = atomicAdd(&lcnt[b], 1);
        int slot = lscan[b] + lidx;
        uint2 p;
        p.x = ((uint32_t)(r & (BROWS - 1)) << 18) | (uint32_t)cols[e0 + i];
        p.y = ftoi(vals[e0 + i]);
        stage[slot] = p;
        slotb[slot] = (u16)b;
    }
    __syncthreads();
    for (int s = tid; s < nE; s += 256) {
        int b = slotb[s];
        etmp[gstart[b] + (s - lscan[b])] = stage[s];
    }
}

// ---------------- pass 2: per-bucket row count + LDS scan -> row_ptr; exact placement ----------------
// 293 blocks x 512 threads (512-row buckets) -> >1 block/CU, ~16K edges/block.
__global__ __launch_bounds__(512) void k_place2(const int* __restrict__ bucket_base,
                                                const uint2* __restrict__ etmp,
                                                int* __restrict__ row_ptr,
                                                uint2* __restrict__ efin) {
    __shared__ int lcnt[BROWS];
    __shared__ int lcur[BROWS];
    __shared__ int wsum[8];
    int b = blockIdx.x;
    int tid = threadIdx.x;
    int base = b << BSHIFT;
    int bstart = bucket_base[b];
    int bend   = bucket_base[b + 1];
    lcnt[tid] = 0;
    __syncthreads();
    for (int i = bstart + tid; i < bend; i += 512)
        atomicAdd(&lcnt[etmp[i].x >> 18], 1);
    __syncthreads();
    int c = lcnt[tid];
    int lane = tid & 63, wid = tid >> 6;
    int v = c;
    for (int off = 1; off < 64; off <<= 1) {
        int u = __shfl_up(v, off, 64);
        if (lane >= off) v += u;
    }
    if (lane == 63) wsum[wid] = v;
    __syncthreads();
    if (tid == 0) {
        int acc = 0;
        for (int w = 0; w < 8; ++w) { int t = wsum[w]; wsum[w] = acc; acc += t; }
    }
    __syncthreads();
    int ex = wsum[wid] + (v - c);
    int gpos = bstart + ex;
    if (base + tid < N_NODES) row_ptr[base + tid] = gpos;
    lcur[tid] = gpos;
    __syncthreads();
    for (int i = bstart + tid; i < bend; i += 512) {
        uint2 p = etmp[i];
        int rl = (int)(p.x >> 18);
        int pos = atomicAdd(&lcur[rl], 1);
        uint2 o; o.x = p.x & 0x3FFFFu; o.y = p.y;
        efin[pos] = o;   // within a 1-block-owned 131 KB window -> L2-combined
    }
}

// ---------------- fused weight transposes fp32 -> bf16 (all segments are 32768) ----------------
__global__ __launch_bounds__(256) void k_transpose3(const float* __restrict__ W1,
                                                    const float* __restrict__ W2,
                                                    const float* __restrict__ P1,
                                                    u16* __restrict__ WT1,
                                                    u16* __restrict__ WT2,
                                                    u16* __restrict__ PT1) {
    int gi = blockIdx.x * 256 + threadIdx.x;
    int seg = gi >> 15;           // /32768
    int i = gi & 32767;
    const float* W; u16* WT; int K, N;
    if (seg == 0)      { W = W1; WT = WT1; K = D0;     N = H1; }
    else if (seg == 1) { W = W2; WT = WT2; K = H1;     N = H2; }
    else               { W = P1; WT = PT1; K = 2 * H2; N = H2; }
    int k = i / N, n = i - k * N;
    WT[n * K + k] = f2bf(W[i]);
}

// ---------------- BN prep: raw sums (double) -> per-feature scale/shift ----------------
__global__ __launch_bounds__(256) void k_bnprep(const double* __restrict__ stats,
                                                const float* __restrict__ g,
                                                const float* __restrict__ beta,
                                                float* __restrict__ sc,
                                                float* __restrict__ sh, int NF) {
    int f = blockIdx.x * 256 + threadIdx.x;
    if (f >= NF) return;
    double mu = stats[f] * (1.0 / N_NODES);
    double var = stats[NF + f] * (1.0 / N_NODES) - mu * mu;
    float s = rsqrtf((float)var + EPSV) * g[f];
    sc[f] = s;
    sh[f] = beta[f] - (float)mu * s;
}

// ---------------- standalone BN stats for layer 2 (round-0 proven shape; double out) ----
__global__ __launch_bounds__(256) void k_bnstats(const u16* __restrict__ agg,
                                                 double* __restrict__ stats, int NF) {
    int tid = threadIdx.x;
    int rpb = 256 / NF;
    int f = tid & (NF - 1);
    int r0 = blockIdx.x * rpb + tid / NF;
    int rs = gridDim.x * rpb;
    float s = 0.f, s2 = 0.f;
    for (int row = r0; row < N_NODES; row += rs) {
        float v = bf2f(agg[(size_t)row * NF + f]);
        s += v; s2 += v * v;
    }
    atomicAdd(&stats[f], (double)s);
    atomicAdd(&stats[NF + f], (double)s2);
}

// ---------------- MFMA GEMM v2: 512 threads, 128 rows/block, full-N staged ----------------
// 8 waves/block + launch_bounds(512,4) -> 4 waves/SIMD; plain cached A-loads.
// B^T in 64 KB LDS, XOR swizzle (elem ^ ((row&7)<<3)).
// Optional: fused A-side BN+ReLU (BNF), fused column stats (STATS, double), rowscale bias.
template<int NJ, int KK, bool BNF, bool RELU, bool STATS>
__global__ __launch_bounds__(512, 4) void k_gemmN(const u16* __restrict__ A, int M,
                                                  const u16* __restrict__ BT,
                                                  const float* __restrict__ bias,
                                                  const float* __restrict__ rowscale,
                                                  const float* __restrict__ bnsc,
                                                  const float* __restrict__ bnsh,
                                                  double* __restrict__ stats,
                                                  u16* __restrict__ C) {
    constexpr int NN = NJ * 16;                 // 256 or 128
    __shared__ u16 lbt[NN * KK];                // always 64 KB
    constexpr int CPR = KK / 8;                 // uint4 chunks per row (16 or 32)
    int tid = threadIdx.x;
    int lane = tid & 63, wid = tid >> 6;        // wid 0..7
    int m0 = blockIdx.x * 128;

    // stage B^T (shared across all blocks -> keep cached), swizzled
    for (int idx = tid; idx < NN * CPR; idx += 512) {
        int r = idx / CPR, c = idx - r * CPR;
        int dst = (r * KK + c * 8) ^ ((r & 7) << 3);
        *(uint4*)(void*)(lbt + dst) = *(const uint4*)(const void*)(BT + (size_t)r * KK + c * 8);
    }
    __syncthreads();

    int rn = lane & 15;
    int kq = (lane >> 4) * 8;
    int mrow = m0 + wid * 16 + rn;
    int mclamp = mrow < M ? mrow : M - 1;
    const u16* aptr = A + (size_t)mclamp * KK + kq;
    int swz = (rn & 7) << 3;

    floatx4 acc[NJ];
    #pragma unroll
    for (int j = 0; j < NJ; ++j) acc[j] = (floatx4){0.f, 0.f, 0.f, 0.f};

    #pragma unroll
    for (int kt = 0; kt < KK; kt += 32) {
        short8 a = *(const short8*)(const void*)(aptr + kt);   // plain cached load
        if constexpr (BNF) {
            // elementwise on register values BEFORE the MFMA consumes them: a[j] holds
            // A[mrow][kq+kt+j] by construction of the load, so bnsc[kq+kt+j] is correct
            // regardless of the MFMA's internal k mapping.
            float4 s0 = *(const float4*)(const void*)(bnsc + kq + kt);
            float4 s1 = *(const float4*)(const void*)(bnsc + kq + kt + 4);
            float4 h0 = *(const float4*)(const void*)(bnsh + kq + kt);
            float4 h1 = *(const float4*)(const void*)(bnsh + kq + kt + 4);
            float v0 = fmaxf(bf2f((u16)a[0]) * s0.x + h0.x, 0.f);
            float v1 = fmaxf(bf2f((u16)a[1]) * s0.y + h0.y, 0.f);
            float v2 = fmaxf(bf2f((u16)a[2]) * s0.z + h0.z, 0.f);
            float v3 = fmaxf(bf2f((u16)a[3]) * s0.w + h0.w, 0.f);
            float v4 = fmaxf(bf2f((u16)a[4]) * s1.x + h1.x, 0.f);
            float v5 = fmaxf(bf2f((u16)a[5]) * s1.y + h1.y, 0.f);
            float v6 = fmaxf(bf2f((u16)a[6]) * s1.z + h1.z, 0.f);
            float v7 = fmaxf(bf2f((u16)a[7]) * s1.w + h1.w, 0.f);
            union { short8 s; u16 u[8]; } ua;
            ua.u[0] = f2bf(v0); ua.u[1] = f2bf(v1);   // RNE, identical to round-0 chain
            ua.u[2] = f2bf(v2); ua.u[3] = f2bf(v3);
            ua.u[4] = f2bf(v4); ua.u[5] = f2bf(v5);
            ua.u[6] = f2bf(v6); ua.u[7] = f2bf(v7);
            a = ua.s;
        }
        #pragma unroll
        for (int j = 0; j < NJ; ++j) {
            const u16* bp = lbt + ((j * 16 + rn) * KK + ((kq + kt) ^ swz));
            short8 b = *(const short8*)(const void*)bp;
            acc[j] = __builtin_amdgcn_mfma_f32_16x16x32_bf16(a, b, acc[j], 0, 0, 0);
        }
    }

    float* sred = (float*)lbt;                  // overlay after compute
    if constexpr (STATS) {
        __syncthreads();
        for (int i = tid; i < 2 * NN; i += 512) sred[i] = 0.f;
        __syncthreads();
    }

    int rbase = m0 + wid * 16 + (lane >> 4) * 4;   // C/D: col=lane&15, row=(lane>>4)*4+i
    float rsv[4];
    #pragma unroll
    for (int i = 0; i < 4; ++i) {
        int row = rbase + i;
        rsv[i] = rowscale ? rowscale[row < M ? row : M - 1] : 1.0f;
    }
    #pragma unroll
    for (int j = 0; j < NJ; ++j) {
        int col = j * 16 + rn;
        float bs = bias[col];
        float vs = 0.f, vq = 0.f;
        #pragma unroll
        for (int i = 0; i < 4; ++i) {
            int row = rbase + i;
            float v = acc[j][i] + rsv[i] * bs;
            if constexpr (RELU) v = v < 0.f ? 0.f : v;
            if (row < M) {
                u16 cb = f2bf(v);
                C[(size_t)row * NN + col] = cb;
                if constexpr (STATS) { float vr = bf2f(cb); vs += vr; vq += vr * vr; }
            }
        }
        if constexpr (STATS) {
            atomicAdd(&sred[col], vs);
            atomicAdd(&sred[NN + col], vq);
        }
    }
    if constexpr (STATS) {
        __syncthreads();
        for (int i = tid; i < 2 * NN; i += 512)
            atomicAdd(&stats[i], (double)sred[i]);   // double: replay-stable ordering noise
    }
}

// ---------------- aggregation, XCD feature-sliced ----------------
// Round-7 structural change: slice = blockIdx.x & 7 (8 slices x 16 features). Under the
// MI300-family round-robin workgroup->XCD dispatch, all blocks of slice s land on XCD s,
// shrinking the per-XCD gather working set from 38.4 MB to 4.8 MB (~ its 4 MB L2).
// Per lane: 2 lanes per row (h = lane&1, 8 features each), 32 rows/wave, 128 rows/block.
// Accumulation order per feature is BIT-IDENTICAL to the round-6 kernel (same CSR walk,
// same unroll-4, same parenthesization). No epilogue state in body (round-3 rule).
__device__ inline void accum8(float* acc, uint4 r, float v) {
    acc[0] += v * bf2f((u16)(r.x & 0xffffu)); acc[1] += v * bf2f((u16)(r.x >> 16));
    acc[2] += v * bf2f((u16)(r.y & 0xffffu)); acc[3] += v * bf2f((u16)(r.y >> 16));
    acc[4] += v * bf2f((u16)(r.z & 0xffffu)); acc[5] += v * bf2f((u16)(r.z >> 16));
    acc[6] += v * bf2f((u16)(r.w & 0xffffu)); acc[7] += v * bf2f((u16)(r.w >> 16));
}

__global__ __launch_bounds__(256) void k_agg(const u16* __restrict__ t,
                                             const int* __restrict__ row_ptr,
                                             const uint2* __restrict__ edges,
                                             u16* __restrict__ agg,
                                             float* __restrict__ rowsum) {
    int bid = blockIdx.x;
    int slice = bid & 7;                 // XCD affinity under round-robin dispatch
    int rb = bid >> 3;                   // row-block (128 rows)
    int tid = threadIdx.x;
    int lane = tid & 63;
    int h = lane & 1;                    // 16-byte half of the 32-byte slice
    int row = rb * 128 + (tid >> 6) * 32 + (lane >> 1);
    if (row >= N_NODES) return;
    float acc[8] = {0.f,0.f,0.f,0.f,0.f,0.f,0.f,0.f};
    float sv = 0.f;
    int s = row_ptr[row], e = row_ptr[row + 1];
    const u16* tf = t + slice * 16 + h * 8;
    int i = s;
    for (; i + 4 <= e; i += 4) {
        uint2 e0 = edges[i], e1 = edges[i+1], e2 = edges[i+2], e3 = edges[i+3];
        uint4 r0 = *(const uint4*)(const void*)(tf + (size_t)e0.x * 128);
        uint4 r1 = *(const uint4*)(const void*)(tf + (size_t)e1.x * 128);
        uint4 r2 = *(const uint4*)(const void*)(tf + (size_t)e2.x * 128);
        uint4 r3 = *(const uint4*)(const void*)(tf + (size_t)e3.x * 128);
        float v0 = itof(e0.y), v1 = itof(e1.y), v2 = itof(e2.y), v3 = itof(e3.y);
        accum8(acc, r0, v0); accum8(acc, r1, v1);
        accum8(acc, r2, v2); accum8(acc, r3, v3);
        sv += v0 + v1 + v2 + v3;
    }
    for (; i < e; ++i) {
        uint2 e0 = edges[i];
        uint4 r0 = *(const uint4*)(const void*)(tf + (size_t)e0.x * 128);
        float v0 = itof(e0.y);
        accum8(acc, r0, v0);
        sv += v0;
    }
    uint4 w;
    w.x = pack2(acc[0], acc[1]); w.y = pack2(acc[2], acc[3]);
    w.z = pack2(acc[4], acc[5]); w.w = pack2(acc[6], acc[7]);
    *(uint4*)(void*)(agg + (size_t)row * 128 + slice * 16 + h * 8) = w;
    if (rowsum != nullptr && slice == 0 && h == 0) rowsum[row] = sv;
}

// ---------------- gather u||v with fused BN2+ReLU -> comb [B,256] bf16 ----------------
__global__ __launch_bounds__(256) void k_gatherBN(const int* __restrict__ ui,
                                                  const int* __restrict__ ii,
                                                  const u16* __restrict__ agg2,
                                                  const double* __restrict__ stats,
                                                  const float* __restrict__ g,
                                                  const float* __restrict__ beta,
                                                  u16* __restrict__ comb) {
    int item = blockIdx.x * 4 + (threadIdx.x >> 6);
    int lane = threadIdx.x & 63;
    if (item >= BATCH) return;
    int node = (lane < 32) ? ui[item] : (N_USERS + ii[item]);
    int fb = (lane & 31) * 4;
    uint2 r = *(const uint2*)(const void*)(agg2 + (size_t)node * H2 + fb);
    float vv[4] = { bf2f((u16)(r.x & 0xffffu)), bf2f((u16)(r.x >> 16)),
                    bf2f((u16)(r.y & 0xffffu)), bf2f((u16)(r.y >> 16)) };
    u16 o[4];
    for (int j = 0; j < 4; ++j) {
        int f = fb + j;
        double mu = stats[f] * (1.0 / N_NODES);
        double var = stats[H2 + f] * (1.0 / N_NODES) - mu * mu;
        float sc = rsqrtf((float)var + EPSV) * g[f];
        float v = ((float)(vv[j] - mu)) * sc + beta[f];
        o[j] = f2bf(v < 0.f ? 0.f : v);
    }
    uint2 w;
    w.x = (uint32_t)o[0] | ((uint32_t)o[1] << 16);
    w.y = (uint32_t)o[2] | ((uint32_t)o[3] << 16);
    *(uint2*)(void*)(comb + (size_t)item * (2 * H2) + lane * 4) = w;
}

// ---------------- final dot ----------------
__global__ __launch_bounds__(256) void k_final(const u16* __restrict__ h,
                                               const float* __restrict__ P2,
                                               const float* __restrict__ pb2,
                                               float* __restrict__ out) {
    int item = blockIdx.x * 4 + (threadIdx.x >> 6);
    int lane = threadIdx.x & 63;
    if (item >= BATCH) return;
    float a = bf2f(h[(size_t)item * H2 + lane])      * P2[lane]
            + bf2f(h[(size_t)item * H2 + 64 + lane]) * P2[64 + lane];
    for (int off = 32; off > 0; off >>= 1) a += __shfl_down(a, off, 64);
    if (lane == 0) out[item] = a + pb2[0];
}

extern "C" void kernel_launch(void* const* d_in, const int* in_sizes, int n_in,
                              void* d_out, int out_size, void* d_ws, size_t ws_size,
                              hipStream_t stream) {
    (void)in_sizes; (void)n_in; (void)ws_size;
    const int* user_indices = (const int*)d_in[0];
    const int* item_indices = (const int*)d_in[1];
    const int* edge_rows    = (const int*)d_in[2];
    const int* edge_cols    = (const int*)d_in[3];
    const float* edge_vals = (const float*)d_in[4];
    const float* user_emb  = (const float*)d_in[5];
    const float* item_emb  = (const float*)d_in[6];
    const float* W1    = (const float*)d_in[7];
    const float* b1    = (const float*)d_in[8];
    const float* g1    = (const float*)d_in[9];
    const float* beta1 = (const float*)d_in[10];
    const float* W2    = (const float*)d_in[11];
    const float* b2    = (const float*)d_in[12];
    const float* g2    = (const float*)d_in[13];
    const float* beta2 = (const float*)d_in[14];
    const float* P1    = (const float*)d_in[15];
    const float* pb1   = (const float*)d_in[16];
    const float* P2    = (const float*)d_in[17];
    const float* pb2   = (const float*)d_in[18];
    float* out = (float*)d_out;

    // workspace layout (~195 MB)
    char* ws = (char*)d_ws;
    size_t off = 0;
    auto alloc = [&](size_t bytes) -> char* {
        char* p = ws + off;
        off = (off + bytes + 255) & ~(size_t)255;
        return p;
    };
    int*   row_ptr  = (int*)alloc(sizeof(int) * (N_NODES + 1));
    int*   bcount   = (int*)alloc(sizeof(int) * (NBUCK + 1));
    int*   bbase    = (int*)alloc(sizeof(int) * (NBUCK + 1));
    int*   bcursor  = (int*)alloc(sizeof(int) * (NBUCK + 1));
    float* rowsum   = (float*)alloc(sizeof(float) * N_NODES);
    double* stats1  = (double*)alloc(sizeof(double) * 2 * H1);
    double* stats2  = (double*)alloc(sizeof(double) * 2 * H2);
    float* sc1      = (float*)alloc(sizeof(float) * H1);
    float* sh1      = (float*)alloc(sizeof(float) * H1);
    u16* WT1 = (u16*)alloc(2 * D0 * H1);
    u16* WT2 = (u16*)alloc(2 * H1 * H2);
    u16* PT1 = (u16*)alloc(2 * 2 * H2 * H2);
    uint2* efin = (uint2*)alloc(8 * (size_t)NEDGE);     // final CSR edges
    // R1 (76.8 MB): xb | aggx ; later t2 reuses xb's slot (xb dead after agg1)
    u16* R1   = (u16*)alloc(2 * (size_t)N_NODES * H1);
    u16* xb   = R1;
    u16* aggx = R1 + (size_t)N_NODES * D0;
    u16* t2   = R1;                                      // 38.4 MB, after gemm1
    // R2 (76.8 MB): etmp (sort scratch) -> agg1 (full) -> {comb+hbuf | agg2}
    u16* R2   = (u16*)alloc(2 * (size_t)N_NODES * H1);
    uint2* etmp = (uint2*)R2;                            // 38.4 MB, dead after k_place2
    u16* agg1 = R2;                                      // [N,256] = full R2
    u16* agg2 = R2 + (size_t)N_NODES * H2;               // upper half (agg1 dead by then)
    u16* comb = R2;                                      // lower: 8.4 MB
    u16* hbuf = R2 + (size_t)BATCH * 2 * H2;             // lower: +4.2 MB

    const int AGG_GRID = ((N_NODES + 127) / 128) * 8;    // row-blocks x 8 XCD slices

    // fused init (canary 2.0 + zero bcount/stats)
    k_init<<<(out_size + 255) / 256, 256, 0, stream>>>(out, out_size, bcount, stats1, stats2);

    // x -> bf16
    k_cvt<<<(N_NODES * D0 / 4 + 255) / 256, 256, 0, stream>>>(user_emb, item_emb, xb);

    // CSR build: bucket-count -> scan(293) -> bucket stage -> place (+row_ptr)
    k_bcount<<<(NEDGE + CCHUNK - 1) / CCHUNK, 256, 0, stream>>>(edge_rows, bcount);
    k_bscan<<<1, 512, 0, stream>>>(bcount, bbase, bcursor, row_ptr);
    k_bucket<<<(NEDGE + BCHUNK - 1) / BCHUNK, 256, 0, stream>>>(
        edge_rows, edge_cols, edge_vals, bcursor, etmp);
    k_place2<<<NBUCK, 512, 0, stream>>>(bbase, etmp, row_ptr, efin);

    // fused weight transposes fp32 -> bf16 (B^T layout)
    k_transpose3<<<(3 * 32768) / 256, 256, 0, stream>>>(W1, W2, P1, WT1, WT2, PT1);

    // layer 1 (agg-then-GEMM via linearity): aggx = agg(xb); agg1 = aggx@W1 + s_r*b1
    // stats1 (col sum/sumsq of bf16-rounded agg1) fused into gemm1 epilogue.
    k_agg<<<AGG_GRID, 256, 0, stream>>>(xb, row_ptr, efin, aggx, rowsum);
    k_gemmN<16, 128, false, false, true><<<(N_NODES + 127) / 128, 512, 0, stream>>>(
        aggx, N_NODES, WT1, b1, rowsum, nullptr, nullptr, stats1, agg1);
    k_bnprep<<<1, 256, 0, stream>>>(stats1, g1, beta1, sc1, sh1, H1);

    // layer 2: t2 = relu(bn1(agg1)) @ W2 + b2  (BN1+ReLU fused into A-path; x1 never materialized)
    k_gemmN<8, 256, true, false, false><<<(N_NODES + 127) / 128, 512, 0, stream>>>(
        agg1, N_NODES, WT2, b2, nullptr, sc1, sh1, nullptr, t2);
    // agg2 = agg(t2); stats2 standalone (keeps k_agg's proven body free of epilogue state)
    k_agg<<<AGG_GRID, 256, 0, stream>>>(t2, row_ptr, efin, agg2, nullptr);
    k_bnstats<<<512, 256, 0, stream>>>(agg2, stats2, H2);

    // head: gather with fused BN2+ReLU, MLP, dot
    k_gatherBN<<<BATCH / 4, 256, 0, stream>>>(user_indices, item_indices, agg2,
                                              stats2, g2, beta2, comb);
    k_gemmN<8, 256, false, true, false><<<BATCH / 128, 512, 0, stream>>>(
        comb, BATCH, PT1, pb1, nullptr, nullptr, nullptr, nullptr, hbuf);
    k_final<<<BATCH / 4, 256, 0, stream>>>(hbuf, P2, pb2, out);
}

// Round 8
// 924.691 us; speedup vs baseline: 2.3104x; 2.3104x over previous
//
#include <hip/hip_runtime.h>
#include <stdint.h>

#define N_USERS 100000
#define N_NODES 150000
#define D0      128
#define H1      256
#define H2      128
#define NEDGE   4800000
#define BATCH   16384
#define EPSV    1e-5f
#define BSHIFT  9            // 512-row buckets
#define BROWS   512
#define NBUCK   293          // ceil(150000/512)
#define BCHUNK  4096         // edges per k_bucket block
#define CCHUNK  16384        // edges per k_bcount block

typedef short short8  __attribute__((ext_vector_type(8)));   // 8 bf16 MFMA frag
typedef float floatx4 __attribute__((ext_vector_type(4)));
typedef unsigned short u16;

__device__ inline float bf2f(u16 u) {
    union { float f; uint32_t i; } x; x.i = ((uint32_t)u) << 16; return x.f;
}
__device__ inline u16 f2bf(float f) {
    union { float f; uint32_t i; } x; x.f = f;
    return (u16)((x.i + 0x7FFFu + ((x.i >> 16) & 1u)) >> 16);  // RNE
}
__device__ inline float itof(uint32_t u) {
    union { float f; uint32_t i; } x; x.i = u; return x.f;
}
__device__ inline uint32_t ftoi(float f) {
    union { float f; uint32_t i; } x; x.f = f; return x.i;
}
__device__ inline uint32_t pack2(float a, float b) {
    return (uint32_t)f2bf(a) | ((uint32_t)f2bf(b) << 16);
}

// ---------------- fused init: canary + zeros ----------------
__global__ __launch_bounds__(256) void k_init(float* __restrict__ out, int out_n,
                                              int* __restrict__ bcount,
                                              double* __restrict__ stats1,
                                              double* __restrict__ stats2) {
    int i = blockIdx.x * 256 + threadIdx.x;
    if (i < out_n) out[i] = 2.0f;               // canary
    if (i < NBUCK + 1) bcount[i] = 0;
    if (i < 2 * H1) stats1[i] = 0.0;
    if (i < 2 * H2) stats2[i] = 0.0;
}

// ---------------- x (fp32 user||item) -> bf16 xb ----------------
__global__ __launch_bounds__(256) void k_cvt(const float* __restrict__ ue,
                                             const float* __restrict__ ie,
                                             u16* __restrict__ xb) {
    int i = (blockIdx.x * 256 + threadIdx.x) * 4;
    const int NU = N_USERS * D0;
    const int NT = N_NODES * D0;
    if (i >= NT) return;
    const float* src = (i < NU) ? (ue + i) : (ie + (i - NU));
    float4 f = *(const float4*)(const void*)src;
    uint2 w;
    w.x = pack2(f.x, f.y);
    w.y = pack2(f.z, f.w);
    *(uint2*)(void*)(xb + i) = w;
}

// ---------------- bucket counting: LDS histogram of 293 buckets ----------------
__global__ __launch_bounds__(256) void k_bcount(const int* __restrict__ rows,
                                                int* __restrict__ bcount) {
    __shared__ int h[NBUCK];
    int tid = threadIdx.x;
    for (int i = tid; i < NBUCK; i += 256) h[i] = 0;
    __syncthreads();
    int e0 = blockIdx.x * CCHUNK;
    int nE = NEDGE - e0; if (nE > CCHUNK) nE = CCHUNK;
    for (int i = tid; i < nE; i += 256) atomicAdd(&h[rows[e0 + i] >> BSHIFT], 1);
    __syncthreads();
    for (int i = tid; i < NBUCK; i += 256)
        if (h[i] > 0) atomicAdd(&bcount[i], h[i]);
}

// single-block (512t) scan of bucket counts -> bucket_base / bucket_cursor; row_ptr[N]=NEDGE
__global__ __launch_bounds__(512) void k_bscan(const int* __restrict__ bcount,
                                               int* __restrict__ bucket_base,
                                               int* __restrict__ bucket_cursor,
                                               int* __restrict__ row_ptr) {
    int tid = threadIdx.x;
    int c = (tid < NBUCK) ? bcount[tid] : 0;
    int lane = tid & 63, wid = tid >> 6;
    int v = c;
    for (int off = 1; off < 64; off <<= 1) {
        int u = __shfl_up(v, off, 64);
        if (lane >= off) v += u;
    }
    __shared__ int wsum[8];
    if (lane == 63) wsum[wid] = v;
    __syncthreads();
    if (tid == 0) {
        int acc = 0;
        for (int w = 0; w < 8; ++w) { int t = wsum[w]; wsum[w] = acc; acc += t; }
    }
    __syncthreads();
    int ex = wsum[wid] + (v - c);
    if (tid < NBUCK) { bucket_base[tid] = ex; bucket_cursor[tid] = ex; }
    if (tid == 0) { bucket_base[NBUCK] = NEDGE; row_ptr[N_NODES] = NEDGE; }
}

// ---------------- pass 1: LDS-staged bucket append (coalesced spans) ----------------
// payload packed: x = (rowlocal<<18) | col  (9b rowlocal + 18b col), y = val bits
__global__ __launch_bounds__(256) void k_bucket(const int* __restrict__ rows,
                                                const int* __restrict__ cols,
                                                const float* __restrict__ vals,
                                                int* __restrict__ bucket_cursor,
                                                uint2* __restrict__ etmp) {
    __shared__ uint2 stage[BCHUNK];        // 32 KB
    __shared__ u16   slotb[BCHUNK];        // 8 KB
    __shared__ int   lcnt[NBUCK + 1];
    __shared__ int   lscan[NBUCK + 1];
    __shared__ int   gstart[NBUCK];
    __shared__ int   wsum[8];
    int tid = threadIdx.x;
    int e0 = blockIdx.x * BCHUNK;
    int nE = NEDGE - e0; if (nE > BCHUNK) nE = BCHUNK;

    for (int i = tid; i <= NBUCK; i += 256) lcnt[i] = 0;
    __syncthreads();
    for (int i = tid; i < nE; i += 256) atomicAdd(&lcnt[rows[e0 + i] >> BSHIFT], 1);
    __syncthreads();
    // two-round wave scan over 293 entries using 256 threads (handle idx and idx+256)
    {
        int lane = tid & 63, wid = tid >> 6;
        int c0 = lcnt[tid];
        int c1 = (tid + 256 <= NBUCK) ? lcnt[tid + 256] : 0;   // lcnt has NBUCK+1 slots
        if (tid < NBUCK) gstart[tid] = atomicAdd(&bucket_cursor[tid], c0);
        if (tid + 256 < NBUCK) gstart[tid + 256] = atomicAdd(&bucket_cursor[tid + 256], c1);
        int v = c0;
        for (int off = 1; off < 64; off <<= 1) {
            int u = __shfl_up(v, off, 64);
            if (lane >= off) v += u;
        }
        if (lane == 63) wsum[wid] = v;
        __syncthreads();
        int v1 = c1;
        for (int off = 1; off < 64; off <<= 1) {
            int u = __shfl_up(v1, off, 64);
            if (lane >= off) v1 += u;
        }
        if (lane == 63) wsum[4 + wid] = v1;
        __syncthreads();
        if (tid == 0) {
            int acc = 0;
            for (int w = 0; w < 8; ++w) { int t = wsum[w]; wsum[w] = acc; acc += t; }
        }
        __syncthreads();
        if (tid < NBUCK) lscan[tid] = wsum[wid] + (v - c0);
        if (tid + 256 < NBUCK) lscan[tid + 256] = wsum[4 + wid] + (v1 - c1);
        __syncthreads();
        for (int i = tid; i < NBUCK; i += 256) lcnt[i] = 0;
    }
    __syncthreads();
    for (int i = tid; i < nE; i += 256) {
        int r = rows[e0 + i];
        int b = r >> BSHIFT;
        int lidx = atomicAdd(&lcnt[b], 1);
        int slot = lscan[b] + lidx;
        uint2 p;
        p.x = ((uint32_t)(r & (BROWS - 1)) << 18) | (uint32_t)cols[e0 + i];
        p.y = ftoi(vals[e0 + i]);
        stage[slot] = p;
        slotb[slot] = (u16)b;
    }
    __syncthreads();
    for (int s = tid; s < nE; s += 256) {
        int b = slotb[s];
        etmp[gstart[b] + (s - lscan[b])] = stage[s];
    }
}

// ---------------- pass 2: per-bucket row count + LDS scan -> row_ptr; exact placement ----------------
// 293 blocks x 512 threads (512-row buckets) -> >1 block/CU, ~16K edges/block.
__global__ __launch_bounds__(512) void k_place2(const int* __restrict__ bucket_base,
                                                const uint2* __restrict__ etmp,
                                                int* __restrict__ row_ptr,
                                                uint2* __restrict__ efin) {
    __shared__ int lcnt[BROWS];
    __shared__ int lcur[BROWS];
    __shared__ int wsum[8];
    int b = blockIdx.x;
    int tid = threadIdx.x;
    int base = b << BSHIFT;
    int bstart = bucket_base[b];
    int bend   = bucket_base[b + 1];
    lcnt[tid] = 0;
    __syncthreads();
    for (int i = bstart + tid; i < bend; i += 512)
        atomicAdd(&lcnt[etmp[i].x >> 18], 1);
    __syncthreads();
    int c = lcnt[tid];
    int lane = tid & 63, wid = tid >> 6;
    int v = c;
    for (int off = 1; off < 64; off <<= 1) {
        int u = __shfl_up(v, off, 64);
        if (lane >= off) v += u;
    }
    if (lane == 63) wsum[wid] = v;
    __syncthreads();
    if (tid == 0) {
        int acc = 0;
        for (int w = 0; w < 8; ++w) { int t = wsum[w]; wsum[w] = acc; acc += t; }
    }
    __syncthreads();
    int ex = wsum[wid] + (v - c);
    int gpos = bstart + ex;
    if (base + tid < N_NODES) row_ptr[base + tid] = gpos;
    lcur[tid] = gpos;
    __syncthreads();
    for (int i = bstart + tid; i < bend; i += 512) {
        uint2 p = etmp[i];
        int rl = (int)(p.x >> 18);
        int pos = atomicAdd(&lcur[rl], 1);
        uint2 o; o.x = p.x & 0x3FFFFu; o.y = p.y;
        efin[pos] = o;   // within a 1-block-owned 131 KB window -> L2-combined
    }
}

// ---------------- fused weight transposes fp32 -> bf16 (all segments are 32768) ----------------
__global__ __launch_bounds__(256) void k_transpose3(const float* __restrict__ W1,
                                                    const float* __restrict__ W2,
                                                    const float* __restrict__ P1,
                                                    u16* __restrict__ WT1,
                                                    u16* __restrict__ WT2,
                                                    u16* __restrict__ PT1) {
    int gi = blockIdx.x * 256 + threadIdx.x;
    int seg = gi >> 15;           // /32768
    int i = gi & 32767;
    const float* W; u16* WT; int K, N;
    if (seg == 0)      { W = W1; WT = WT1; K = D0;     N = H1; }
    else if (seg == 1) { W = W2; WT = WT2; K = H1;     N = H2; }
    else               { W = P1; WT = PT1; K = 2 * H2; N = H2; }
    int k = i / N, n = i - k * N;
    WT[n * K + k] = f2bf(W[i]);
}

// ---------------- BN prep: raw sums (double) -> per-feature scale/shift ----------------
__global__ __launch_bounds__(256) void k_bnprep(const double* __restrict__ stats,
                                                const float* __restrict__ g,
                                                const float* __restrict__ beta,
                                                float* __restrict__ sc,
                                                float* __restrict__ sh, int NF) {
    int f = blockIdx.x * 256 + threadIdx.x;
    if (f >= NF) return;
    double mu = stats[f] * (1.0 / N_NODES);
    double var = stats[NF + f] * (1.0 / N_NODES) - mu * mu;
    float s = rsqrtf((float)var + EPSV) * g[f];
    sc[f] = s;
    sh[f] = beta[f] - (float)mu * s;
}

// ---------------- standalone BN stats for layer 2 (round-0 proven shape; double out) ----
__global__ __launch_bounds__(256) void k_bnstats(const u16* __restrict__ agg,
                                                 double* __restrict__ stats, int NF) {
    int tid = threadIdx.x;
    int rpb = 256 / NF;
    int f = tid & (NF - 1);
    int r0 = blockIdx.x * rpb + tid / NF;
    int rs = gridDim.x * rpb;
    float s = 0.f, s2 = 0.f;
    for (int row = r0; row < N_NODES; row += rs) {
        float v = bf2f(agg[(size_t)row * NF + f]);
        s += v; s2 += v * v;
    }
    atomicAdd(&stats[f], (double)s);
    atomicAdd(&stats[NF + f], (double)s2);
}

// ---------------- MFMA GEMM v2: 512 threads, 128 rows/block, full-N staged ----------------
// 8 waves/block + launch_bounds(512,4) -> 4 waves/SIMD; plain cached A-loads.
// B^T in 64 KB LDS, XOR swizzle (elem ^ ((row&7)<<3)).
// Optional: fused A-side BN+ReLU (BNF), fused column stats (STATS, double), rowscale bias.
template<int NJ, int KK, bool BNF, bool RELU, bool STATS>
__global__ __launch_bounds__(512, 4) void k_gemmN(const u16* __restrict__ A, int M,
                                                  const u16* __restrict__ BT,
                                                  const float* __restrict__ bias,
                                                  const float* __restrict__ rowscale,
                                                  const float* __restrict__ bnsc,
                                                  const float* __restrict__ bnsh,
                                                  double* __restrict__ stats,
                                                  u16* __restrict__ C) {
    constexpr int NN = NJ * 16;                 // 256 or 128
    __shared__ u16 lbt[NN * KK];                // always 64 KB
    constexpr int CPR = KK / 8;                 // uint4 chunks per row (16 or 32)
    int tid = threadIdx.x;
    int lane = tid & 63, wid = tid >> 6;        // wid 0..7
    int m0 = blockIdx.x * 128;

    // stage B^T (shared across all blocks -> keep cached), swizzled
    for (int idx = tid; idx < NN * CPR; idx += 512) {
        int r = idx / CPR, c = idx - r * CPR;
        int dst = (r * KK + c * 8) ^ ((r & 7) << 3);
        *(uint4*)(void*)(lbt + dst) = *(const uint4*)(const void*)(BT + (size_t)r * KK + c * 8);
    }
    __syncthreads();

    int rn = lane & 15;
    int kq = (lane >> 4) * 8;
    int mrow = m0 + wid * 16 + rn;
    int mclamp = mrow < M ? mrow : M - 1;
    const u16* aptr = A + (size_t)mclamp * KK + kq;
    int swz = (rn & 7) << 3;

    floatx4 acc[NJ];
    #pragma unroll
    for (int j = 0; j < NJ; ++j) acc[j] = (floatx4){0.f, 0.f, 0.f, 0.f};

    #pragma unroll
    for (int kt = 0; kt < KK; kt += 32) {
        short8 a = *(const short8*)(const void*)(aptr + kt);   // plain cached load
        if constexpr (BNF) {
            // elementwise on register values BEFORE the MFMA consumes them: a[j] holds
            // A[mrow][kq+kt+j] by construction of the load, so bnsc[kq+kt+j] is correct
            // regardless of the MFMA's internal k mapping.
            float4 s0 = *(const float4*)(const void*)(bnsc + kq + kt);
            float4 s1 = *(const float4*)(const void*)(bnsc + kq + kt + 4);
            float4 h0 = *(const float4*)(const void*)(bnsh + kq + kt);
            float4 h1 = *(const float4*)(const void*)(bnsh + kq + kt + 4);
            float v0 = fmaxf(bf2f((u16)a[0]) * s0.x + h0.x, 0.f);
            float v1 = fmaxf(bf2f((u16)a[1]) * s0.y + h0.y, 0.f);
            float v2 = fmaxf(bf2f((u16)a[2]) * s0.z + h0.z, 0.f);
            float v3 = fmaxf(bf2f((u16)a[3]) * s0.w + h0.w, 0.f);
            float v4 = fmaxf(bf2f((u16)a[4]) * s1.x + h1.x, 0.f);
            float v5 = fmaxf(bf2f((u16)a[5]) * s1.y + h1.y, 0.f);
            float v6 = fmaxf(bf2f((u16)a[6]) * s1.z + h1.z, 0.f);
            float v7 = fmaxf(bf2f((u16)a[7]) * s1.w + h1.w, 0.f);
            union { short8 s; u16 u[8]; } ua;
            ua.u[0] = f2bf(v0); ua.u[1] = f2bf(v1);   // RNE, identical to round-0 chain
            ua.u[2] = f2bf(v2); ua.u[3] = f2bf(v3);
            ua.u[4] = f2bf(v4); ua.u[5] = f2bf(v5);
            ua.u[6] = f2bf(v6); ua.u[7] = f2bf(v7);
            a = ua.s;
        }
        #pragma unroll
        for (int j = 0; j < NJ; ++j) {
            const u16* bp = lbt + ((j * 16 + rn) * KK + ((kq + kt) ^ swz));
            short8 b = *(const short8*)(const void*)bp;
            acc[j] = __builtin_amdgcn_mfma_f32_16x16x32_bf16(a, b, acc[j], 0, 0, 0);
        }
    }

    float* sred = (float*)lbt;                  // overlay after compute
    if constexpr (STATS) {
        __syncthreads();
        for (int i = tid; i < 2 * NN; i += 512) sred[i] = 0.f;
        __syncthreads();
    }

    int rbase = m0 + wid * 16 + (lane >> 4) * 4;   // C/D: col=lane&15, row=(lane>>4)*4+i
    float rsv[4];
    #pragma unroll
    for (int i = 0; i < 4; ++i) {
        int row = rbase + i;
        rsv[i] = rowscale ? rowscale[row < M ? row : M - 1] : 1.0f;
    }
    #pragma unroll
    for (int j = 0; j < NJ; ++j) {
        int col = j * 16 + rn;
        float bs = bias[col];
        float vs = 0.f, vq = 0.f;
        #pragma unroll
        for (int i = 0; i < 4; ++i) {
            int row = rbase + i;
            float v = acc[j][i] + rsv[i] * bs;
            if constexpr (RELU) v = v < 0.f ? 0.f : v;
            if (row < M) {
                u16 cb = f2bf(v);
                C[(size_t)row * NN + col] = cb;
                if constexpr (STATS) { float vr = bf2f(cb); vs += vr; vq += vr * vr; }
            }
        }
        if constexpr (STATS) {
            atomicAdd(&sred[col], vs);
            atomicAdd(&sred[NN + col], vq);
        }
    }
    if constexpr (STATS) {
        __syncthreads();
        for (int i = tid; i < 2 * NN; i += 512)
            atomicAdd(&stats[i], (double)sred[i]);   // double: replay-stable ordering noise
    }
}

// ---------------- aggregation (NF=128): 4 rows/wave, 16 lanes/row, uint4 gathers ----------------
// ARCHITECTURAL PLATEAU — round-6 proven body (172 us, 3.7 TB/s, FETCH 586 MB). Verified
// dead ends: nt loads (r2: 2.4x), fused stats epilogue (r3: 2.1x), unroll-8 (r5: neutral),
// XCD feature-slicing (r7: 4.6x — line-granularity duplication across XCD L2s). Do not touch.
__device__ inline void accum8(float* acc, uint4 r, float v) {
    acc[0] += v * bf2f((u16)(r.x & 0xffffu)); acc[1] += v * bf2f((u16)(r.x >> 16));
    acc[2] += v * bf2f((u16)(r.y & 0xffffu)); acc[3] += v * bf2f((u16)(r.y >> 16));
    acc[4] += v * bf2f((u16)(r.z & 0xffffu)); acc[5] += v * bf2f((u16)(r.z >> 16));
    acc[6] += v * bf2f((u16)(r.w & 0xffffu)); acc[7] += v * bf2f((u16)(r.w >> 16));
}

__global__ __launch_bounds__(256) void k_agg(const u16* __restrict__ t,
                                             const int* __restrict__ row_ptr,
                                             const uint2* __restrict__ edges,
                                             u16* __restrict__ agg,
                                             float* __restrict__ rowsum) {
    int tid = threadIdx.x;
    int lane = tid & 63;
    int sub = lane >> 4;                 // row slot within wave (0..3)
    int l16 = lane & 15;                 // feature-lane within row
    int row = blockIdx.x * 16 + (tid >> 6) * 4 + sub;   // 150000/16 = 9375 blocks exact
    float acc[8] = {0.f,0.f,0.f,0.f,0.f,0.f,0.f,0.f};
    float sv = 0.f;
    int s = row_ptr[row], e = row_ptr[row + 1];
    const u16* tf = t + l16 * 8;
    int i = s;
    for (; i + 4 <= e; i += 4) {
        uint2 e0 = edges[i], e1 = edges[i+1], e2 = edges[i+2], e3 = edges[i+3];
        uint4 r0 = *(const uint4*)(const void*)(tf + (size_t)e0.x * 128);
        uint4 r1 = *(const uint4*)(const void*)(tf + (size_t)e1.x * 128);
        uint4 r2 = *(const uint4*)(const void*)(tf + (size_t)e2.x * 128);
        uint4 r3 = *(const uint4*)(const void*)(tf + (size_t)e3.x * 128);
        float v0 = itof(e0.y), v1 = itof(e1.y), v2 = itof(e2.y), v3 = itof(e3.y);
        accum8(acc, r0, v0); accum8(acc, r1, v1);
        accum8(acc, r2, v2); accum8(acc, r3, v3);
        sv += v0 + v1 + v2 + v3;
    }
    for (; i < e; ++i) {
        uint2 e0 = edges[i];
        uint4 r0 = *(const uint4*)(const void*)(tf + (size_t)e0.x * 128);
        float v0 = itof(e0.y);
        accum8(acc, r0, v0);
        sv += v0;
    }
    uint4 w;
    w.x = pack2(acc[0], acc[1]); w.y = pack2(acc[2], acc[3]);
    w.z = pack2(acc[4], acc[5]); w.w = pack2(acc[6], acc[7]);
    *(uint4*)(void*)(agg + (size_t)row * 128 + l16 * 8) = w;
    if (rowsum != nullptr && l16 == 0) rowsum[row] = sv;
}

// ---------------- gather u||v with fused BN2+ReLU -> comb [B,256] bf16 ----------------
__global__ __launch_bounds__(256) void k_gatherBN(const int* __restrict__ ui,
                                                  const int* __restrict__ ii,
                                                  const u16* __restrict__ agg2,
                                                  const double* __restrict__ stats,
                                                  const float* __restrict__ g,
                                                  const float* __restrict__ beta,
                                                  u16* __restrict__ comb) {
    int item = blockIdx.x * 4 + (threadIdx.x >> 6);
    int lane = threadIdx.x & 63;
    if (item >= BATCH) return;
    int node = (lane < 32) ? ui[item] : (N_USERS + ii[item]);
    int fb = (lane & 31) * 4;
    uint2 r = *(const uint2*)(const void*)(agg2 + (size_t)node * H2 + fb);
    float vv[4] = { bf2f((u16)(r.x & 0xffffu)), bf2f((u16)(r.x >> 16)),
                    bf2f((u16)(r.y & 0xffffu)), bf2f((u16)(r.y >> 16)) };
    u16 o[4];
    for (int j = 0; j < 4; ++j) {
        int f = fb + j;
        double mu = stats[f] * (1.0 / N_NODES);
        double var = stats[H2 + f] * (1.0 / N_NODES) - mu * mu;
        float sc = rsqrtf((float)var + EPSV) * g[f];
        float v = ((float)(vv[j] - mu)) * sc + beta[f];
        o[j] = f2bf(v < 0.f ? 0.f : v);
    }
    uint2 w;
    w.x = (uint32_t)o[0] | ((uint32_t)o[1] << 16);
    w.y = (uint32_t)o[2] | ((uint32_t)o[3] << 16);
    *(uint2*)(void*)(comb + (size_t)item * (2 * H2) + lane * 4) = w;
}

// ---------------- final dot ----------------
__global__ __launch_bounds__(256) void k_final(const u16* __restrict__ h,
                                               const float* __restrict__ P2,
                                               const float* __restrict__ pb2,
                                               float* __restrict__ out) {
    int item = blockIdx.x * 4 + (threadIdx.x >> 6);
    int lane = threadIdx.x & 63;
    if (item >= BATCH) return;
    float a = bf2f(h[(size_t)item * H2 + lane])      * P2[lane]
            + bf2f(h[(size_t)item * H2 + 64 + lane]) * P2[64 + lane];
    for (int off = 32; off > 0; off >>= 1) a += __shfl_down(a, off, 64);
    if (lane == 0) out[item] = a + pb2[0];
}

extern "C" void kernel_launch(void* const* d_in, const int* in_sizes, int n_in,
                              void* d_out, int out_size, void* d_ws, size_t ws_size,
                              hipStream_t stream) {
    (void)in_sizes; (void)n_in; (void)ws_size;
    const int* user_indices = (const int*)d_in[0];
    const int* item_indices = (const int*)d_in[1];
    const int* edge_rows    = (const int*)d_in[2];
    const int* edge_cols    = (const int*)d_in[3];
    const float* edge_vals = (const float*)d_in[4];
    const float* user_emb  = (const float*)d_in[5];
    const float* item_emb  = (const float*)d_in[6];
    const float* W1    = (const float*)d_in[7];
    const float* b1    = (const float*)d_in[8];
    const float* g1    = (const float*)d_in[9];
    const float* beta1 = (const float*)d_in[10];
    const float* W2    = (const float*)d_in[11];
    const float* b2    = (const float*)d_in[12];
    const float* g2    = (const float*)d_in[13];
    const float* beta2 = (const float*)d_in[14];
    const float* P1    = (const float*)d_in[15];
    const float* pb1   = (const float*)d_in[16];
    const float* P2    = (const float*)d_in[17];
    const float* pb2   = (const float*)d_in[18];
    float* out = (float*)d_out;

    // workspace layout (~195 MB)
    char* ws = (char*)d_ws;
    size_t off = 0;
    auto alloc = [&](size_t bytes) -> char* {
        char* p = ws + off;
        off = (off + bytes + 255) & ~(size_t)255;
        return p;
    };
    int*   row_ptr  = (int*)alloc(sizeof(int) * (N_NODES + 1));
    int*   bcount   = (int*)alloc(sizeof(int) * (NBUCK + 1));
    int*   bbase    = (int*)alloc(sizeof(int) * (NBUCK + 1));
    int*   bcursor  = (int*)alloc(sizeof(int) * (NBUCK + 1));
    float* rowsum   = (float*)alloc(sizeof(float) * N_NODES);
    double* stats1  = (double*)alloc(sizeof(double) * 2 * H1);
    double* stats2  = (double*)alloc(sizeof(double) * 2 * H2);
    float* sc1      = (float*)alloc(sizeof(float) * H1);
    float* sh1      = (float*)alloc(sizeof(float) * H1);
    u16* WT1 = (u16*)alloc(2 * D0 * H1);
    u16* WT2 = (u16*)alloc(2 * H1 * H2);
    u16* PT1 = (u16*)alloc(2 * 2 * H2 * H2);
    uint2* efin = (uint2*)alloc(8 * (size_t)NEDGE);     // final CSR edges
    // R1 (76.8 MB): xb | aggx ; later t2 reuses xb's slot (xb dead after agg1)
    u16* R1   = (u16*)alloc(2 * (size_t)N_NODES * H1);
    u16* xb   = R1;
    u16* aggx = R1 + (size_t)N_NODES * D0;
    u16* t2   = R1;                                      // 38.4 MB, after gemm1
    // R2 (76.8 MB): etmp (sort scratch) -> agg1 (full) -> {comb+hbuf | agg2}
    u16* R2   = (u16*)alloc(2 * (size_t)N_NODES * H1);
    uint2* etmp = (uint2*)R2;                            // 38.4 MB, dead after k_place2
    u16* agg1 = R2;                                      // [N,256] = full R2
    u16* agg2 = R2 + (size_t)N_NODES * H2;               // upper half (agg1 dead by then)
    u16* comb = R2;                                      // lower: 8.4 MB
    u16* hbuf = R2 + (size_t)BATCH * 2 * H2;             // lower: +4.2 MB

    // fused init (canary 2.0 + zero bcount/stats)
    k_init<<<(out_size + 255) / 256, 256, 0, stream>>>(out, out_size, bcount, stats1, stats2);

    // x -> bf16
    k_cvt<<<(N_NODES * D0 / 4 + 255) / 256, 256, 0, stream>>>(user_emb, item_emb, xb);

    // CSR build: bucket-count -> scan(293) -> bucket stage -> place (+row_ptr)
    k_bcount<<<(NEDGE + CCHUNK - 1) / CCHUNK, 256, 0, stream>>>(edge_rows, bcount);
    k_bscan<<<1, 512, 0, stream>>>(bcount, bbase, bcursor, row_ptr);
    k_bucket<<<(NEDGE + BCHUNK - 1) / BCHUNK, 256, 0, stream>>>(
        edge_rows, edge_cols, edge_vals, bcursor, etmp);
    k_place2<<<NBUCK, 512, 0, stream>>>(bbase, etmp, row_ptr, efin);

    // fused weight transposes fp32 -> bf16 (B^T layout)
    k_transpose3<<<(3 * 32768) / 256, 256, 0, stream>>>(W1, W2, P1, WT1, WT2, PT1);

    // layer 1 (agg-then-GEMM via linearity): aggx = agg(xb); agg1 = aggx@W1 + s_r*b1
    // stats1 (col sum/sumsq of bf16-rounded agg1) fused into gemm1 epilogue.
    k_agg<<<N_NODES / 16, 256, 0, stream>>>(xb, row_ptr, efin, aggx, rowsum);
    k_gemmN<16, 128, false, false, true><<<(N_NODES + 127) / 128, 512, 0, stream>>>(
        aggx, N_NODES, WT1, b1, rowsum, nullptr, nullptr, stats1, agg1);
    k_bnprep<<<1, 256, 0, stream>>>(stats1, g1, beta1, sc1, sh1, H1);

    // layer 2: t2 = relu(bn1(agg1)) @ W2 + b2  (BN1+ReLU fused into A-path; x1 never materialized)
    k_gemmN<8, 256, true, false, false><<<(N_NODES + 127) / 128, 512, 0, stream>>>(
        agg1, N_NODES, WT2, b2, nullptr, sc1, sh1, nullptr, t2);
    // agg2 = agg(t2); stats2 standalone (keeps k_agg's proven body free of epilogue state)
    k_agg<<<N_NODES / 16, 256, 0, stream>>>(t2, row_ptr, efin, agg2, nullptr);
    k_bnstats<<<512, 256, 0, stream>>>(agg2, stats2, H2);

    // head: gather with fused BN2+ReLU, MLP, dot
    k_gatherBN<<<BATCH / 4, 256, 0, stream>>>(user_indices, item_indices, agg2,
                                              stats2, g2, beta2, comb);
    k_gemmN<8, 256, false, true, false><<<BATCH / 128, 512, 0, stream>>>(
        comb, BATCH, PT1, pb1, nullptr, nullptr, nullptr, nullptr, hbuf);
    k_final<<<BATCH / 4, 256, 0, stream>>>(hbuf, P2, pb2, out);
}

// Round 9
// 909.604 us; speedup vs baseline: 2.3487x; 1.0166x over previous
//
#include <hip/hip_runtime.h>
#include <stdint.h>

#define N_USERS 100000
#define N_NODES 150000
#define D0      128
#define H1      256
#define H2      128
#define NEDGE   4800000
#define BATCH   16384
#define EPSV    1e-5f
#define BSHIFT  9            // 512-row buckets
#define BROWS   512
#define NBUCK   293          // ceil(150000/512)
#define BCHUNK  4096         // edges per k_bucket block
#define CCHUNK  16384        // edges per bcount range block

// k_prep block-range split
#define CVT_BLKS  18750      // 150000*128/4/256
#define BCNT_BLKS 293        // (NEDGE+CCHUNK-1)/CCHUNK
#define T3_BLKS   384        // 3*32768/256

typedef short short8  __attribute__((ext_vector_type(8)));   // 8 bf16 MFMA frag
typedef float floatx4 __attribute__((ext_vector_type(4)));
typedef unsigned short u16;

__device__ inline float bf2f(u16 u) {
    union { float f; uint32_t i; } x; x.i = ((uint32_t)u) << 16; return x.f;
}
__device__ inline u16 f2bf(float f) {
    union { float f; uint32_t i; } x; x.f = f;
    return (u16)((x.i + 0x7FFFu + ((x.i >> 16) & 1u)) >> 16);  // RNE
}
__device__ inline float itof(uint32_t u) {
    union { float f; uint32_t i; } x; x.i = u; return x.f;
}
__device__ inline uint32_t ftoi(float f) {
    union { float f; uint32_t i; } x; x.f = f; return x.i;
}
__device__ inline uint32_t pack2(float a, float b) {
    return (uint32_t)f2bf(a) | ((uint32_t)f2bf(b) << 16);
}

// ---------------- fused init: canary + zeros (must run BEFORE k_prep's bcount atomics) ----
__global__ __launch_bounds__(256) void k_init(float* __restrict__ out, int out_n,
                                              int* __restrict__ bcount,
                                              double* __restrict__ stats1,
                                              double* __restrict__ stats2) {
    int i = blockIdx.x * 256 + threadIdx.x;
    if (i < out_n) out[i] = 2.0f;               // canary
    if (i < NBUCK + 1) bcount[i] = 0;
    if (i < 2 * H1) stats1[i] = 0.0;
    if (i < 2 * H2) stats2[i] = 0.0;
}

// ---------------- merged prep: cvt | bcount | transpose3 (independent, block-range split) ----
__global__ __launch_bounds__(256) void k_prep(const float* __restrict__ ue,
                                              const float* __restrict__ ie,
                                              u16* __restrict__ xb,
                                              const int* __restrict__ rows,
                                              int* __restrict__ bcount,
                                              const float* __restrict__ W1,
                                              const float* __restrict__ W2,
                                              const float* __restrict__ P1,
                                              u16* __restrict__ WT1,
                                              u16* __restrict__ WT2,
                                              u16* __restrict__ PT1) {
    __shared__ int h[NBUCK];
    int b = blockIdx.x;
    int tid = threadIdx.x;
    if (b < CVT_BLKS) {
        // ---- x (fp32 user||item) -> bf16 xb ----
        int i = (b * 256 + tid) * 4;
        const int NU = N_USERS * D0;
        const int NT = N_NODES * D0;
        if (i >= NT) return;
        const float* src = (i < NU) ? (ue + i) : (ie + (i - NU));
        float4 f = *(const float4*)(const void*)src;
        uint2 w;
        w.x = pack2(f.x, f.y);
        w.y = pack2(f.z, f.w);
        *(uint2*)(void*)(xb + i) = w;
    } else if (b < CVT_BLKS + BCNT_BLKS) {
        // ---- bucket counting: LDS histogram of 293 buckets ----
        int lb = b - CVT_BLKS;
        for (int i = tid; i < NBUCK; i += 256) h[i] = 0;
        __syncthreads();
        int e0 = lb * CCHUNK;
        int nE = NEDGE - e0; if (nE > CCHUNK) nE = CCHUNK;
        for (int i = tid; i < nE; i += 256) atomicAdd(&h[rows[e0 + i] >> BSHIFT], 1);
        __syncthreads();
        for (int i = tid; i < NBUCK; i += 256)
            if (h[i] > 0) atomicAdd(&bcount[i], h[i]);
    } else {
        // ---- weight transposes fp32 -> bf16 (all segments are 32768) ----
        int gi = (b - CVT_BLKS - BCNT_BLKS) * 256 + tid;
        int seg = gi >> 15;           // /32768
        int i = gi & 32767;
        const float* W; u16* WT; int K, N;
        if (seg == 0)      { W = W1; WT = WT1; K = D0;     N = H1; }
        else if (seg == 1) { W = W2; WT = WT2; K = H1;     N = H2; }
        else               { W = P1; WT = PT1; K = 2 * H2; N = H2; }
        int k = i / N, n = i - k * N;
        WT[n * K + k] = f2bf(W[i]);
    }
}

// single-block (512t) scan of bucket counts -> bucket_base / bucket_cursor; row_ptr[N]=NEDGE
__global__ __launch_bounds__(512) void k_bscan(const int* __restrict__ bcount,
                                               int* __restrict__ bucket_base,
                                               int* __restrict__ bucket_cursor,
                                               int* __restrict__ row_ptr) {
    int tid = threadIdx.x;
    int c = (tid < NBUCK) ? bcount[tid] : 0;
    int lane = tid & 63, wid = tid >> 6;
    int v = c;
    for (int off = 1; off < 64; off <<= 1) {
        int u = __shfl_up(v, off, 64);
        if (lane >= off) v += u;
    }
    __shared__ int wsum[8];
    if (lane == 63) wsum[wid] = v;
    __syncthreads();
    if (tid == 0) {
        int acc = 0;
        for (int w = 0; w < 8; ++w) { int t = wsum[w]; wsum[w] = acc; acc += t; }
    }
    __syncthreads();
    int ex = wsum[wid] + (v - c);
    if (tid < NBUCK) { bucket_base[tid] = ex; bucket_cursor[tid] = ex; }
    if (tid == 0) { bucket_base[NBUCK] = NEDGE; row_ptr[N_NODES] = NEDGE; }
}

// ---------------- pass 1: LDS-staged bucket append (coalesced spans) ----------------
// payload packed: x = (rowlocal<<18) | col  (9b rowlocal + 18b col), y = val bits
__global__ __launch_bounds__(256) void k_bucket(const int* __restrict__ rows,
                                                const int* __restrict__ cols,
                                                const float* __restrict__ vals,
                                                int* __restrict__ bucket_cursor,
                                                uint2* __restrict__ etmp) {
    __shared__ uint2 stage[BCHUNK];        // 32 KB
    __shared__ u16   slotb[BCHUNK];        // 8 KB
    __shared__ int   lcnt[NBUCK + 1];
    __shared__ int   lscan[NBUCK + 1];
    __shared__ int   gstart[NBUCK];
    __shared__ int   wsum[8];
    int tid = threadIdx.x;
    int e0 = blockIdx.x * BCHUNK;
    int nE = NEDGE - e0; if (nE > BCHUNK) nE = BCHUNK;

    for (int i = tid; i <= NBUCK; i += 256) lcnt[i] = 0;
    __syncthreads();
    for (int i = tid; i < nE; i += 256) atomicAdd(&lcnt[rows[e0 + i] >> BSHIFT], 1);
    __syncthreads();
    // two-round wave scan over 293 entries using 256 threads (handle idx and idx+256)
    {
        int lane = tid & 63, wid = tid >> 6;
        int c0 = lcnt[tid];
        int c1 = (tid + 256 <= NBUCK) ? lcnt[tid + 256] : 0;   // lcnt has NBUCK+1 slots
        if (tid < NBUCK) gstart[tid] = atomicAdd(&bucket_cursor[tid], c0);
        if (tid + 256 < NBUCK) gstart[tid + 256] = atomicAdd(&bucket_cursor[tid + 256], c1);
        int v = c0;
        for (int off = 1; off < 64; off <<= 1) {
            int u = __shfl_up(v, off, 64);
            if (lane >= off) v += u;
        }
        if (lane == 63) wsum[wid] = v;
        __syncthreads();
        int v1 = c1;
        for (int off = 1; off < 64; off <<= 1) {
            int u = __shfl_up(v1, off, 64);
            if (lane >= off) v1 += u;
        }
        if (lane == 63) wsum[4 + wid] = v1;
        __syncthreads();
        if (tid == 0) {
            int acc = 0;
            for (int w = 0; w < 8; ++w) { int t = wsum[w]; wsum[w] = acc; acc += t; }
        }
        __syncthreads();
        if (tid < NBUCK) lscan[tid] = wsum[wid] + (v - c0);
        if (tid + 256 < NBUCK) lscan[tid + 256] = wsum[4 + wid] + (v1 - c1);
        __syncthreads();
        for (int i = tid; i < NBUCK; i += 256) lcnt[i] = 0;
    }
    __syncthreads();
    for (int i = tid; i < nE; i += 256) {
        int r = rows[e0 + i];
        int b = r >> BSHIFT;
        int lidx = atomicAdd(&lcnt[b], 1);
        int slot = lscan[b] + lidx;
        uint2 p;
        p.x = ((uint32_t)(r & (BROWS - 1)) << 18) | (uint32_t)cols[e0 + i];
        p.y = ftoi(vals[e0 + i]);
        stage[slot] = p;
        slotb[slot] = (u16)b;
    }
    __syncthreads();
    for (int s = tid; s < nE; s += 256) {
        int b = slotb[s];
        etmp[gstart[b] + (s - lscan[b])] = stage[s];
    }
}

// ---------------- pass 2: per-bucket row count + LDS scan -> row_ptr; exact placement ----------------
// 293 blocks x 512 threads (512-row buckets) -> >1 block/CU, ~16K edges/block.
__global__ __launch_bounds__(512) void k_place2(const int* __restrict__ bucket_base,
                                                const uint2* __restrict__ etmp,
                                                int* __restrict__ row_ptr,
                                                uint2* __restrict__ efin) {
    __shared__ int lcnt[BROWS];
    __shared__ int lcur[BROWS];
    __shared__ int wsum[8];
    int b = blockIdx.x;
    int tid = threadIdx.x;
    int base = b << BSHIFT;
    int bstart = bucket_base[b];
    int bend   = bucket_base[b + 1];
    lcnt[tid] = 0;
    __syncthreads();
    for (int i = bstart + tid; i < bend; i += 512)
        atomicAdd(&lcnt[etmp[i].x >> 18], 1);
    __syncthreads();
    int c = lcnt[tid];
    int lane = tid & 63, wid = tid >> 6;
    int v = c;
    for (int off = 1; off < 64; off <<= 1) {
        int u = __shfl_up(v, off, 64);
        if (lane >= off) v += u;
    }
    if (lane == 63) wsum[wid] = v;
    __syncthreads();
    if (tid == 0) {
        int acc = 0;
        for (int w = 0; w < 8; ++w) { int t = wsum[w]; wsum[w] = acc; acc += t; }
    }
    __syncthreads();
    int ex = wsum[wid] + (v - c);
    int gpos = bstart + ex;
    if (base + tid < N_NODES) row_ptr[base + tid] = gpos;
    lcur[tid] = gpos;
    __syncthreads();
    for (int i = bstart + tid; i < bend; i += 512) {
        uint2 p = etmp[i];
        int rl = (int)(p.x >> 18);
        int pos = atomicAdd(&lcur[rl], 1);
        uint2 o; o.x = p.x & 0x3FFFFu; o.y = p.y;
        efin[pos] = o;   // within a 1-block-owned 131 KB window -> L2-combined
    }
}

// ---------------- standalone BN stats for layer 2 (round-0 proven shape; double out) ----
__global__ __launch_bounds__(256) void k_bnstats(const u16* __restrict__ agg,
                                                 double* __restrict__ stats, int NF) {
    int tid = threadIdx.x;
    int rpb = 256 / NF;
    int f = tid & (NF - 1);
    int r0 = blockIdx.x * rpb + tid / NF;
    int rs = gridDim.x * rpb;
    float s = 0.f, s2 = 0.f;
    for (int row = r0; row < N_NODES; row += rs) {
        float v = bf2f(agg[(size_t)row * NF + f]);
        s += v; s2 += v * v;
    }
    atomicAdd(&stats[f], (double)s);
    atomicAdd(&stats[NF + f], (double)s2);
}

// ---------------- MFMA GEMM v3: 512 threads, 128 rows/block, full-N staged ----------------
// 8 waves/block + launch_bounds(512,4); plain cached A-loads; B^T in 64 KB LDS with XOR
// swizzle (elem ^ ((row&7)<<3)). Options:
//  BNF:    per-block BN-prep (sc/sh computed from double stats into 2 KB LDS — identical
//          math to the old k_bnprep) + fused A-side BN+ReLU. Kills the serial bnprep launch.
//  STATS:  fused column sum/sumsq of the bf16-ROUNDED stored C (double accumulation).
//  FINDOT: final-layer fusion — no C store; dot the bf16-rounded relu'd row with P2,
//          16-lane shuffle reduce, write out[row] + pb2. Kills k_final + the hbuf roundtrip.
template<int NJ, int KK, bool BNF, bool RELU, bool STATS, bool FINDOT>
__global__ __launch_bounds__(512, 4) void k_gemmN(const u16* __restrict__ A, int M,
                                                  const u16* __restrict__ BT,
                                                  const float* __restrict__ bias,
                                                  const float* __restrict__ rowscale,
                                                  const double* __restrict__ bnstats_in,
                                                  const float* __restrict__ bng,
                                                  const float* __restrict__ bnbeta,
                                                  double* __restrict__ stats,
                                                  u16* __restrict__ C,
                                                  const float* __restrict__ P2,
                                                  const float* __restrict__ pb2,
                                                  float* __restrict__ outv) {
    constexpr int NN = NJ * 16;                 // 256 or 128
    __shared__ u16 lbt[NN * KK];                // always 64 KB
    __shared__ float sbn[BNF ? 2 * KK : 4];     // BN scale/shift tables (2 KB when BNF)
    constexpr int CPR = KK / 8;                 // uint4 chunks per row (16 or 32)
    int tid = threadIdx.x;
    int lane = tid & 63, wid = tid >> 6;        // wid 0..7
    int m0 = blockIdx.x * 128;

    if constexpr (BNF) {
        // per-block redundant BN-prep (same double math as the old k_bnprep kernel)
        for (int f = tid; f < KK; f += 512) {
            double mu = bnstats_in[f] * (1.0 / N_NODES);
            double var = bnstats_in[KK + f] * (1.0 / N_NODES) - mu * mu;
            float s = rsqrtf((float)var + EPSV) * bng[f];
            sbn[f] = s;
            sbn[KK + f] = bnbeta[f] - (float)mu * s;
        }
    }
    // stage B^T (shared across all blocks -> keep cached), swizzled
    for (int idx = tid; idx < NN * CPR; idx += 512) {
        int r = idx / CPR, c = idx - r * CPR;
        int dst = (r * KK + c * 8) ^ ((r & 7) << 3);
        *(uint4*)(void*)(lbt + dst) = *(const uint4*)(const void*)(BT + (size_t)r * KK + c * 8);
    }
    __syncthreads();

    int rn = lane & 15;
    int kq = (lane >> 4) * 8;
    int mrow = m0 + wid * 16 + rn;
    int mclamp = mrow < M ? mrow : M - 1;
    const u16* aptr = A + (size_t)mclamp * KK + kq;
    int swz = (rn & 7) << 3;

    floatx4 acc[NJ];
    #pragma unroll
    for (int j = 0; j < NJ; ++j) acc[j] = (floatx4){0.f, 0.f, 0.f, 0.f};

    #pragma unroll
    for (int kt = 0; kt < KK; kt += 32) {
        short8 a = *(const short8*)(const void*)(aptr + kt);   // plain cached load
        if constexpr (BNF) {
            // elementwise on register values BEFORE the MFMA consumes them: a[j] holds
            // A[mrow][kq+kt+j] by construction of the load, so sbn[kq+kt+j] is correct
            // regardless of the MFMA's internal k mapping. LDS broadcast reads (same addr
            // across the 16 lanes of a kq-group) are conflict-free.
            float4 s0 = *(const float4*)(const void*)(sbn + kq + kt);
            float4 s1 = *(const float4*)(const void*)(sbn + kq + kt + 4);
            float4 h0 = *(const float4*)(const void*)(sbn + KK + kq + kt);
            float4 h1 = *(const float4*)(const void*)(sbn + KK + kq + kt + 4);
            float v0 = fmaxf(bf2f((u16)a[0]) * s0.x + h0.x, 0.f);
            float v1 = fmaxf(bf2f((u16)a[1]) * s0.y + h0.y, 0.f);
            float v2 = fmaxf(bf2f((u16)a[2]) * s0.z + h0.z, 0.f);
            float v3 = fmaxf(bf2f((u16)a[3]) * s0.w + h0.w, 0.f);
            float v4 = fmaxf(bf2f((u16)a[4]) * s1.x + h1.x, 0.f);
            float v5 = fmaxf(bf2f((u16)a[5]) * s1.y + h1.y, 0.f);
            float v6 = fmaxf(bf2f((u16)a[6]) * s1.z + h1.z, 0.f);
            float v7 = fmaxf(bf2f((u16)a[7]) * s1.w + h1.w, 0.f);
            union { short8 s; u16 u[8]; } ua;
            ua.u[0] = f2bf(v0); ua.u[1] = f2bf(v1);   // RNE, identical to round-0 chain
            ua.u[2] = f2bf(v2); ua.u[3] = f2bf(v3);
            ua.u[4] = f2bf(v4); ua.u[5] = f2bf(v5);
            ua.u[6] = f2bf(v6); ua.u[7] = f2bf(v7);
            a = ua.s;
        }
        #pragma unroll
        for (int j = 0; j < NJ; ++j) {
            const u16* bp = lbt + ((j * 16 + rn) * KK + ((kq + kt) ^ swz));
            short8 b = *(const short8*)(const void*)bp;
            acc[j] = __builtin_amdgcn_mfma_f32_16x16x32_bf16(a, b, acc[j], 0, 0, 0);
        }
    }

    float* sred = (float*)lbt;                  // overlay after compute
    if constexpr (STATS) {
        __syncthreads();
        for (int i = tid; i < 2 * NN; i += 512) sred[i] = 0.f;
        __syncthreads();
    }

    int rbase = m0 + wid * 16 + (lane >> 4) * 4;   // C/D: col=lane&15, row=(lane>>4)*4+i
    float rsv[4];
    #pragma unroll
    for (int i = 0; i < 4; ++i) {
        int row = rbase + i;
        rsv[i] = rowscale ? rowscale[row < M ? row : M - 1] : 1.0f;
    }
    float pdot[4] = {0.f, 0.f, 0.f, 0.f};
    #pragma unroll
    for (int j = 0; j < NJ; ++j) {
        int col = j * 16 + rn;
        float bs = bias[col];
        float pc = FINDOT ? P2[col] : 0.f;
        float vs = 0.f, vq = 0.f;
        #pragma unroll
        for (int i = 0; i < 4; ++i) {
            int row = rbase + i;
            float v = acc[j][i] + rsv[i] * bs;
            if constexpr (RELU) v = v < 0.f ? 0.f : v;
            if (row < M) {
                u16 cb = f2bf(v);
                if constexpr (FINDOT) {
                    pdot[i] += bf2f(cb) * pc;    // same bf16-rounded values k_final consumed
                } else {
                    C[(size_t)row * NN + col] = cb;
                    if constexpr (STATS) { float vr = bf2f(cb); vs += vr; vq += vr * vr; }
                }
            }
        }
        if constexpr (STATS) {
            atomicAdd(&sred[col], vs);
            atomicAdd(&sred[NN + col], vq);
        }
    }
    if constexpr (FINDOT) {
        // reduce over the 16 rn-lanes of each kq-group (xor masks <16 stay in-group)
        #pragma unroll
        for (int m = 1; m < 16; m <<= 1) {
            #pragma unroll
            for (int i = 0; i < 4; ++i) pdot[i] += __shfl_xor(pdot[i], m, 64);
        }
        if (rn == 0) {
            float pb = pb2[0];
            #pragma unroll
            for (int i = 0; i < 4; ++i) {
                int row = rbase + i;
                if (row < M) outv[row] = pdot[i] + pb;
            }
        }
    }
    if constexpr (STATS) {
        __syncthreads();
        for (int i = tid; i < 2 * NN; i += 512)
            atomicAdd(&stats[i], (double)sred[i]);   // double: replay-stable ordering noise
    }
}

// ---------------- aggregation (NF=128): 4 rows/wave, 16 lanes/row, uint4 gathers ----------------
// ARCHITECTURAL PLATEAU — proven body (172-174 us, 3.7 TB/s, FETCH 586 MB ~= minimal fill at
// the random-256B service rate). Verified dead ends: nt loads (r2: 2.4x), fused stats epilogue
// (r3: 2.1x), unroll-8 (r5: neutral), XCD feature-slicing (r7: 4.6x — line-granularity
// duplication across XCD L2s), col-sweep sort (analysis: ref density <1/line/gen -> worse).
// Do not touch.
__device__ inline void accum8(float* acc, uint4 r, float v) {
    acc[0] += v * bf2f((u16)(r.x & 0xffffu)); acc[1] += v * bf2f((u16)(r.x >> 16));
    acc[2] += v * bf2f((u16)(r.y & 0xffffu)); acc[3] += v * bf2f((u16)(r.y >> 16));
    acc[4] += v * bf2f((u16)(r.z & 0xffffu)); acc[5] += v * bf2f((u16)(r.z >> 16));
    acc[6] += v * bf2f((u16)(r.w & 0xffffu)); acc[7] += v * bf2f((u16)(r.w >> 16));
}

__global__ __launch_bounds__(256) void k_agg(const u16* __restrict__ t,
                                             const int* __restrict__ row_ptr,
                                             const uint2* __restrict__ edges,
                                             u16* __restrict__ agg,
                                             float* __restrict__ rowsum) {
    int tid = threadIdx.x;
    int lane = tid & 63;
    int sub = lane >> 4;                 // row slot within wave (0..3)
    int l16 = lane & 15;                 // feature-lane within row
    int row = blockIdx.x * 16 + (tid >> 6) * 4 + sub;   // 150000/16 = 9375 blocks exact
    float acc[8] = {0.f,0.f,0.f,0.f,0.f,0.f,0.f,0.f};
    float sv = 0.f;
    int s = row_ptr[row], e = row_ptr[row + 1];
    const u16* tf = t + l16 * 8;
    int i = s;
    for (; i + 4 <= e; i += 4) {
        uint2 e0 = edges[i], e1 = edges[i+1], e2 = edges[i+2], e3 = edges[i+3];
        uint4 r0 = *(const uint4*)(const void*)(tf + (size_t)e0.x * 128);
        uint4 r1 = *(const uint4*)(const void*)(tf + (size_t)e1.x * 128);
        uint4 r2 = *(const uint4*)(const void*)(tf + (size_t)e2.x * 128);
        uint4 r3 = *(const uint4*)(const void*)(tf + (size_t)e3.x * 128);
        float v0 = itof(e0.y), v1 = itof(e1.y), v2 = itof(e2.y), v3 = itof(e3.y);
        accum8(acc, r0, v0); accum8(acc, r1, v1);
        accum8(acc, r2, v2); accum8(acc, r3, v3);
        sv += v0 + v1 + v2 + v3;
    }
    for (; i < e; ++i) {
        uint2 e0 = edges[i];
        uint4 r0 = *(const uint4*)(const void*)(tf + (size_t)e0.x * 128);
        float v0 = itof(e0.y);
        accum8(acc, r0, v0);
        sv += v0;
    }
    uint4 w;
    w.x = pack2(acc[0], acc[1]); w.y = pack2(acc[2], acc[3]);
    w.z = pack2(acc[4], acc[5]); w.w = pack2(acc[6], acc[7]);
    *(uint4*)(void*)(agg + (size_t)row * 128 + l16 * 8) = w;
    if (rowsum != nullptr && l16 == 0) rowsum[row] = sv;
}

// ---------------- gather u||v with fused BN2+ReLU -> comb [B,256] bf16 ----------------
__global__ __launch_bounds__(256) void k_gatherBN(const int* __restrict__ ui,
                                                  const int* __restrict__ ii,
                                                  const u16* __restrict__ agg2,
                                                  const double* __restrict__ stats,
                                                  const float* __restrict__ g,
                                                  const float* __restrict__ beta,
                                                  u16* __restrict__ comb) {
    int item = blockIdx.x * 4 + (threadIdx.x >> 6);
    int lane = threadIdx.x & 63;
    if (item >= BATCH) return;
    int node = (lane < 32) ? ui[item] : (N_USERS + ii[item]);
    int fb = (lane & 31) * 4;
    uint2 r = *(const uint2*)(const void*)(agg2 + (size_t)node * H2 + fb);
    float vv[4] = { bf2f((u16)(r.x & 0xffffu)), bf2f((u16)(r.x >> 16)),
                    bf2f((u16)(r.y & 0xffffu)), bf2f((u16)(r.y >> 16)) };
    u16 o[4];
    for (int j = 0; j < 4; ++j) {
        int f = fb + j;
        double mu = stats[f] * (1.0 / N_NODES);
        double var = stats[H2 + f] * (1.0 / N_NODES) - mu * mu;
        float sc = rsqrtf((float)var + EPSV) * g[f];
        float v = ((float)(vv[j] - mu)) * sc + beta[f];
        o[j] = f2bf(v < 0.f ? 0.f : v);
    }
    uint2 w;
    w.x = (uint32_t)o[0] | ((uint32_t)o[1] << 16);
    w.y = (uint32_t)o[2] | ((uint32_t)o[3] << 16);
    *(uint2*)(void*)(comb + (size_t)item * (2 * H2) + lane * 4) = w;
}

extern "C" void kernel_launch(void* const* d_in, const int* in_sizes, int n_in,
                              void* d_out, int out_size, void* d_ws, size_t ws_size,
                              hipStream_t stream) {
    (void)in_sizes; (void)n_in; (void)ws_size;
    const int* user_indices = (const int*)d_in[0];
    const int* item_indices = (const int*)d_in[1];
    const int* edge_rows    = (const int*)d_in[2];
    const int* edge_cols    = (const int*)d_in[3];
    const float* edge_vals = (const float*)d_in[4];
    const float* user_emb  = (const float*)d_in[5];
    const float* item_emb  = (const float*)d_in[6];
    const float* W1    = (const float*)d_in[7];
    const float* b1    = (const float*)d_in[8];
    const float* g1    = (const float*)d_in[9];
    const float* beta1 = (const float*)d_in[10];
    const float* W2    = (const float*)d_in[11];
    const float* b2    = (const float*)d_in[12];
    const float* g2    = (const float*)d_in[13];
    const float* beta2 = (const float*)d_in[14];
    const float* P1    = (const float*)d_in[15];
    const float* pb1   = (const float*)d_in[16];
    const float* P2    = (const float*)d_in[17];
    const float* pb2   = (const float*)d_in[18];
    float* out = (float*)d_out;

    // workspace layout (~195 MB)
    char* ws = (char*)d_ws;
    size_t off = 0;
    auto alloc = [&](size_t bytes) -> char* {
        char* p = ws + off;
        off = (off + bytes + 255) & ~(size_t)255;
        return p;
    };
    int*   row_ptr  = (int*)alloc(sizeof(int) * (N_NODES + 1));
    int*   bcount   = (int*)alloc(sizeof(int) * (NBUCK + 1));
    int*   bbase    = (int*)alloc(sizeof(int) * (NBUCK + 1));
    int*   bcursor  = (int*)alloc(sizeof(int) * (NBUCK + 1));
    float* rowsum   = (float*)alloc(sizeof(float) * N_NODES);
    double* stats1  = (double*)alloc(sizeof(double) * 2 * H1);
    double* stats2  = (double*)alloc(sizeof(double) * 2 * H2);
    u16* WT1 = (u16*)alloc(2 * D0 * H1);
    u16* WT2 = (u16*)alloc(2 * H1 * H2);
    u16* PT1 = (u16*)alloc(2 * 2 * H2 * H2);
    uint2* efin = (uint2*)alloc(8 * (size_t)NEDGE);     // final CSR edges
    // R1 (76.8 MB): xb | aggx ; later t2 reuses xb's slot (xb dead after agg1)
    u16* R1   = (u16*)alloc(2 * (size_t)N_NODES * H1);
    u16* xb   = R1;
    u16* aggx = R1 + (size_t)N_NODES * D0;
    u16* t2   = R1;                                      // 38.4 MB, after gemm1
    // R2 (76.8 MB): etmp (sort scratch) -> agg1 (full) -> {comb | agg2}
    u16* R2   = (u16*)alloc(2 * (size_t)N_NODES * H1);
    uint2* etmp = (uint2*)R2;                            // 38.4 MB, dead after k_place2
    u16* agg1 = R2;                                      // [N,256] = full R2
    u16* agg2 = R2 + (size_t)N_NODES * H2;               // upper half (agg1 dead by then)
    u16* comb = R2;                                      // lower: 8.4 MB

    // init (canary 2.0 + zero bcount/stats) — MUST precede k_prep's bcount atomics
    k_init<<<(out_size + 255) / 256, 256, 0, stream>>>(out, out_size, bcount, stats1, stats2);

    // merged prep: x->bf16 | bucket counting | weight transposes (independent work)
    k_prep<<<CVT_BLKS + BCNT_BLKS + T3_BLKS, 256, 0, stream>>>(
        user_emb, item_emb, xb, edge_rows, bcount, W1, W2, P1, WT1, WT2, PT1);

    // CSR build: scan(293) -> bucket stage -> place (+row_ptr)
    k_bscan<<<1, 512, 0, stream>>>(bcount, bbase, bcursor, row_ptr);
    k_bucket<<<(NEDGE + BCHUNK - 1) / BCHUNK, 256, 0, stream>>>(
        edge_rows, edge_cols, edge_vals, bcursor, etmp);
    k_place2<<<NBUCK, 512, 0, stream>>>(bbase, etmp, row_ptr, efin);

    // layer 1 (agg-then-GEMM via linearity): aggx = agg(xb); agg1 = aggx@W1 + s_r*b1
    // stats1 (col sum/sumsq of bf16-rounded agg1) fused into gemm1 epilogue.
    k_agg<<<N_NODES / 16, 256, 0, stream>>>(xb, row_ptr, efin, aggx, rowsum);
    k_gemmN<16, 128, false, false, true, false><<<(N_NODES + 127) / 128, 512, 0, stream>>>(
        aggx, N_NODES, WT1, b1, rowsum, nullptr, nullptr, nullptr, stats1, agg1,
        nullptr, nullptr, nullptr);

    // layer 2: t2 = relu(bn1(agg1)) @ W2 + b2  (BN-prep + BN1+ReLU fused into A-path;
    // x1 never materialized; bnprep launch eliminated)
    k_gemmN<8, 256, true, false, false, false><<<(N_NODES + 127) / 128, 512, 0, stream>>>(
        agg1, N_NODES, WT2, b2, nullptr, stats1, g1, beta1, nullptr, t2,
        nullptr, nullptr, nullptr);
    // agg2 = agg(t2); stats2 standalone (keeps k_agg's proven body free of epilogue state)
    k_agg<<<N_NODES / 16, 256, 0, stream>>>(t2, row_ptr, efin, agg2, nullptr);
    k_bnstats<<<512, 256, 0, stream>>>(agg2, stats2, H2);

    // head: gather with fused BN2+ReLU, then MLP with fused final dot (k_final + hbuf gone)
    k_gatherBN<<<BATCH / 4, 256, 0, stream>>>(user_indices, item_indices, agg2,
                                              stats2, g2, beta2, comb);
    k_gemmN<8, 256, false, true, false, true><<<BATCH / 128, 512, 0, stream>>>(
        comb, BATCH, PT1, pb1, nullptr, nullptr, nullptr, nullptr, nullptr, nullptr,
        P2, pb2, out);
}